// Round 2
// baseline (648.733 us; speedup 1.0000x reference)
//
#include <hip/hip_runtime.h>

#define TOKENS  8192
#define HIDDEN  6144
#define EXPERTS 768
#define TOPK    12
#define RSF     2.5f

typedef float    f4 __attribute__((ext_vector_type(4)));
typedef _Float16 h8 __attribute__((ext_vector_type(8)));
typedef _Float16 h2 __attribute__((ext_vector_type(2)));
typedef __fp16   g2 __attribute__((ext_vector_type(2)));

#define BM 128
#define BN 96
#define BK 32
#define LO_SCALE   4096.0f          // 2^12: keeps lo out of fp16-denormal range
#define LO_INV     2.44140625e-4f   // 2^-12

static __device__ inline h2 pk(float a, float b) {
    g2 r = __builtin_amdgcn_cvt_pkrtz(a, b);
    return __builtin_bit_cast(h2, r);
}

// Convert 8 fp32 -> hi (fp16 RTZ) and lo ((x-hi)*2^12, fp16).
__device__ inline void cvt8(const f4 a, const f4 b, h8& hi, h8& lo) {
    h2 ha = pk(a.x, a.y);
    h2 hb = pk(a.z, a.w);
    h2 hc = pk(b.x, b.y);
    h2 hd = pk(b.z, b.w);
    h2 la = pk((a.x - (float)ha[0]) * LO_SCALE, (a.y - (float)ha[1]) * LO_SCALE);
    h2 lb = pk((a.z - (float)hb[0]) * LO_SCALE, (a.w - (float)hb[1]) * LO_SCALE);
    h2 lc = pk((b.x - (float)hc[0]) * LO_SCALE, (b.y - (float)hc[1]) * LO_SCALE);
    h2 ld = pk((b.z - (float)hd[0]) * LO_SCALE, (b.w - (float)hd[1]) * LO_SCALE);
    hi[0]=ha[0]; hi[1]=ha[1]; hi[2]=hb[0]; hi[3]=hb[1];
    hi[4]=hc[0]; hi[5]=hc[1]; hi[6]=hd[0]; hi[7]=hd[1];
    lo[0]=la[0]; lo[1]=la[1]; lo[2]=lb[0]; lo[3]=lb[1];
    lo[4]=lc[0]; lo[5]=lc[1]; lo[6]=ld[0]; lo[7]=ld[1];
}

// logits[t][e] = sum_h X[t][h] * W[e][h], split-fp16 MFMA (hi*hi + hi*lo + lo*hi).
__global__ __launch_bounds__(256, 2)
void router_gemm(const float* __restrict__ X, const float* __restrict__ W,
                 float* __restrict__ L) {
    __shared__ _Float16 Ah[BM * BK], Al[BM * BK], Bh[BN * BK], Bl[BN * BK];

    const int t    = threadIdx.x;
    const int bm   = blockIdx.y * BM;   // token tile
    const int bn   = blockIdx.x * BN;   // expert tile (gridDim.x == 8 -> XCD pin)
    const int lane = t & 63;
    const int wave = t >> 6;
    const int lr   = lane & 15;
    const int lq   = lane >> 4;
    const int m0   = (wave & 1) * 64;
    const int n0   = (wave >> 1) * 48;

    // staging: threads 0..127 load A rows, 128..223 load B rows
    const bool isA = (t < BM);
    const bool act = (t < BM + BN);
    const float* src = isA ? (X + (size_t)(bm + t) * HIDDEN)
                           : (W + (size_t)(bn + (t - BM)) * HIDDEN);
    _Float16* dh = isA ? (Ah + t * BK) : (Bh + (t - BM) * BK);
    _Float16* dl = isA ? (Al + t * BK) : (Bl + (t - BM) * BK);

    f4 acc_h[4][3];   // hi*hi
    f4 acc_c[4][3];   // hi*lo' + lo'*hi (scaled by 2^12)
#pragma unroll
    for (int i = 0; i < 4; ++i)
#pragma unroll
        for (int j = 0; j < 3; ++j) { acc_h[i][j] = f4{0,0,0,0}; acc_c[i][j] = f4{0,0,0,0}; }

    for (int kt = 0; kt < HIDDEN; kt += BK) {
        f4 v[8];
        if (act) {
            const f4* p = (const f4*)(src + kt);
#pragma unroll
            for (int i = 0; i < 8; ++i) v[i] = p[i];
        }
        __syncthreads();               // previous iteration's LDS reads done
        if (act) {
#pragma unroll
            for (int g = 0; g < 4; ++g) {
                h8 hi, lo;
                cvt8(v[2*g], v[2*g+1], hi, lo);
                *(h8*)(dh + g * 8) = hi;
                *(h8*)(dl + g * 8) = lo;
            }
        }
        __syncthreads();

        h8 ah[4], al[4], bh[3], bl[3];
#pragma unroll
        for (int mi = 0; mi < 4; ++mi) {
            const int r = m0 + mi * 16 + lr;
            ah[mi] = *(const h8*)(Ah + r * BK + lq * 8);
            al[mi] = *(const h8*)(Al + r * BK + lq * 8);
        }
#pragma unroll
        for (int ni = 0; ni < 3; ++ni) {
            const int r = n0 + ni * 16 + lr;
            bh[ni] = *(const h8*)(Bh + r * BK + lq * 8);
            bl[ni] = *(const h8*)(Bl + r * BK + lq * 8);
        }
#pragma unroll
        for (int mi = 0; mi < 4; ++mi)
#pragma unroll
            for (int ni = 0; ni < 3; ++ni) {
                acc_h[mi][ni] = __builtin_amdgcn_mfma_f32_16x16x32_f16(ah[mi], bh[ni], acc_h[mi][ni], 0, 0, 0);
                acc_c[mi][ni] = __builtin_amdgcn_mfma_f32_16x16x32_f16(ah[mi], bl[ni], acc_c[mi][ni], 0, 0, 0);
                acc_c[mi][ni] = __builtin_amdgcn_mfma_f32_16x16x32_f16(al[mi], bh[ni], acc_c[mi][ni], 0, 0, 0);
            }
    }

    // C/D layout: col = lane&15, row = (lane>>4)*4 + reg
#pragma unroll
    for (int mi = 0; mi < 4; ++mi)
#pragma unroll
        for (int ni = 0; ni < 3; ++ni)
#pragma unroll
            for (int r = 0; r < 4; ++r) {
                const int gm = bm + m0 + mi * 16 + lq * 4 + r;
                const int gn = bn + n0 + ni * 16 + lr;
                L[(size_t)gm * EXPERTS + gn] = acc_h[mi][ni][r] + acc_c[mi][ni][r] * LO_INV;
            }
}

// One wave per token: softmax over 768, bias-corrected top-12 (desc, ties -> lower idx).
__global__ __launch_bounds__(256)
void router_topk(const float* __restrict__ L, const float* __restrict__ bias,
                 float* __restrict__ outIdx, float* __restrict__ outW) {
    __shared__ float sb[EXPERTS];
    const int t = threadIdx.x;
    for (int i = t; i < EXPERTS; i += 256) sb[i] = bias[i];
    __syncthreads();

    const int lane  = t & 63;
    const int wave  = t >> 6;
    const int token = blockIdx.x * 4 + wave;
    const float* row = L + (size_t)token * EXPERTS;

    float lg[12];
#pragma unroll
    for (int j = 0; j < 12; ++j) lg[j] = row[lane + 64 * j];

    float m = lg[0];
#pragma unroll
    for (int j = 1; j < 12; ++j) m = fmaxf(m, lg[j]);
#pragma unroll
    for (int o = 32; o > 0; o >>= 1) m = fmaxf(m, __shfl_xor(m, o));

    float s = 0.0f;
#pragma unroll
    for (int j = 0; j < 12; ++j) { lg[j] = __expf(lg[j] - m); s += lg[j]; }
#pragma unroll
    for (int o = 32; o > 0; o >>= 1) s += __shfl_xor(s, o);
    const float inv = 1.0f / s;

    float cand[12];
#pragma unroll
    for (int j = 0; j < 12; ++j) {
        lg[j] *= inv;                          // softmax score
        cand[j] = lg[j] + sb[lane + 64 * j];   // biased choice score
    }

#pragma unroll
    for (int r = 0; r < TOPK; ++r) {
        float bv = -__builtin_inff();
        int   bi = EXPERTS;
#pragma unroll
        for (int j = 0; j < 12; ++j) {
            const int e = lane + 64 * j;
            const bool better = (cand[j] > bv) || (cand[j] == bv && e < bi);
            bv = better ? cand[j] : bv;
            bi = better ? e : bi;
        }
#pragma unroll
        for (int o = 32; o > 0; o >>= 1) {
            const float ov = __shfl_xor(bv, o);
            const int   oi = __shfl_xor(bi, o);
            const bool better = (ov > bv) || (ov == bv && oi < bi);
            bv = better ? ov : bv;
            bi = better ? oi : bi;
        }
        if (lane == 0) {
            outIdx[token * TOPK + r] = (float)bi;
            outW  [token * TOPK + r] = (bv - sb[bi]) * RSF;
        }
        if ((bi & 63) == lane) {
            const int slot = bi >> 6;
#pragma unroll
            for (int j = 0; j < 12; ++j)
                if (j == slot) cand[j] = -__builtin_inff();
        }
    }
}

extern "C" void kernel_launch(void* const* d_in, const int* in_sizes, int n_in,
                              void* d_out, int out_size, void* d_ws, size_t ws_size,
                              hipStream_t stream) {
    const float* X = (const float*)d_in[0];   // [8192, 6144] fp32
    const float* W = (const float*)d_in[1];   // [768, 6144]  fp32
    const float* B = (const float*)d_in[2];   // [768]        fp32

    float* logits = (float*)d_ws;             // 8192*768*4 = 25.2 MB scratch
    float* outIdx = (float*)d_out;            // indices as float values
    float* outW   = outIdx + (size_t)TOKENS * TOPK;

    dim3 grid_gemm(EXPERTS / BN, TOKENS / BM);   // (8, 64) = 512 blocks
    router_gemm<<<grid_gemm, 256, 0, stream>>>(X, W, logits);
    router_topk<<<TOKENS / 4, 256, 0, stream>>>(logits, B, outIdx, outW);
}

// Round 3
// 567.056 us; speedup vs baseline: 1.1440x; 1.1440x over previous
//
#include <hip/hip_runtime.h>

#define TOKENS  8192
#define HIDDEN  6144
#define EXPERTS 768
#define TOPK    12
#define RSF     2.5f

typedef float    f4 __attribute__((ext_vector_type(4)));
typedef _Float16 h8 __attribute__((ext_vector_type(8)));
typedef _Float16 h4 __attribute__((ext_vector_type(4)));
typedef _Float16 h2 __attribute__((ext_vector_type(2)));
typedef __fp16   g2 __attribute__((ext_vector_type(2)));

#define BM 64
#define BN 96
#define BK 32
#define LDST 40                     // LDS row stride in halves (80 B) — kills bank conflicts
#define LO_SCALE   4096.0f          // 2^12: keeps lo out of fp16-denormal range
#define LO_INV     2.44140625e-4f   // 2^-12

static __device__ inline h2 pk(float a, float b) {
    g2 r = __builtin_amdgcn_cvt_pkrtz(a, b);
    return __builtin_bit_cast(h2, r);
}

// fp32x4 -> hi fp16x4 (RTZ) + lo fp16x4 ((x-hi)*2^12)
static __device__ inline void cvt4(const f4 a, h4& hi, h4& lo) {
    h2 h01 = pk(a.x, a.y);
    h2 h23 = pk(a.z, a.w);
    h2 l01 = pk((a.x - (float)h01[0]) * LO_SCALE, (a.y - (float)h01[1]) * LO_SCALE);
    h2 l23 = pk((a.z - (float)h23[0]) * LO_SCALE, (a.w - (float)h23[1]) * LO_SCALE);
    hi[0]=h01[0]; hi[1]=h01[1]; hi[2]=h23[0]; hi[3]=h23[1];
    lo[0]=l01[0]; lo[1]=l01[1]; lo[2]=l23[0]; lo[3]=l23[1];
}

// logits[t][e] = sum_h X[t][h] * W[e][h], split-fp16 MFMA (hi*hi + hi*lo + lo*hi).
__global__ __launch_bounds__(256, 4)
void router_gemm(const float* __restrict__ X, const float* __restrict__ W,
                 float* __restrict__ L) {
    __shared__ _Float16 Ah[BM * LDST], Al[BM * LDST], Bh[BN * LDST], Bl[BN * LDST];

    const int t    = threadIdx.x;
    const int bm   = blockIdx.y * BM;   // token tile (128 tiles)
    const int bn   = blockIdx.x * BN;   // expert tile (8 tiles -> XCD pin)
    const int lane = t & 63;
    const int wave = t >> 6;
    const int lr   = lane & 15;
    const int lq   = lane >> 4;
    const int m0   = (wave & 1) * 32;
    const int n0   = (wave >> 1) * 48;

    // coalesced staging: chunk q = i*256 + t; row = q/8, c = q%8
    // 8 consecutive lanes read 8 consecutive float4 of one row (contiguous 128 B)
    const int c  = t & 7;     // float4 index within the 32-float row chunk
    const int r0 = t >> 3;    // 0..31
    const float* pa0 = X + (size_t)(bm + r0)      * HIDDEN + c * 4;
    const float* pa1 = X + (size_t)(bm + r0 + 32) * HIDDEN + c * 4;
    const float* pb0 = W + (size_t)(bn + r0)      * HIDDEN + c * 4;
    const float* pb1 = W + (size_t)(bn + r0 + 32) * HIDDEN + c * 4;
    const float* pb2 = W + (size_t)(bn + r0 + 64) * HIDDEN + c * 4;

    f4 acc_h[2][3];   // hi*hi
    f4 acc_c[2][3];   // hi*lo + lo*hi (scaled by 2^12)
#pragma unroll
    for (int i = 0; i < 2; ++i)
#pragma unroll
        for (int j = 0; j < 3; ++j) { acc_h[i][j] = f4{0,0,0,0}; acc_c[i][j] = f4{0,0,0,0}; }

    f4 v[5];
    v[0] = *(const f4*)(pa0);
    v[1] = *(const f4*)(pa1);
    v[2] = *(const f4*)(pb0);
    v[3] = *(const f4*)(pb1);
    v[4] = *(const f4*)(pb2);

    for (int kt = 0; kt < HIDDEN; kt += BK) {
        __syncthreads();               // previous iteration's LDS reads done
        {
            h4 hi, lo;
            cvt4(v[0], hi, lo);
            *(h4*)(Ah + (r0     ) * LDST + c * 4) = hi;
            *(h4*)(Al + (r0     ) * LDST + c * 4) = lo;
            cvt4(v[1], hi, lo);
            *(h4*)(Ah + (r0 + 32) * LDST + c * 4) = hi;
            *(h4*)(Al + (r0 + 32) * LDST + c * 4) = lo;
            cvt4(v[2], hi, lo);
            *(h4*)(Bh + (r0     ) * LDST + c * 4) = hi;
            *(h4*)(Bl + (r0     ) * LDST + c * 4) = lo;
            cvt4(v[3], hi, lo);
            *(h4*)(Bh + (r0 + 32) * LDST + c * 4) = hi;
            *(h4*)(Bl + (r0 + 32) * LDST + c * 4) = lo;
            cvt4(v[4], hi, lo);
            *(h4*)(Bh + (r0 + 64) * LDST + c * 4) = hi;
            *(h4*)(Bl + (r0 + 64) * LDST + c * 4) = lo;
        }
        __syncthreads();

        if (kt + BK < HIDDEN) {        // prefetch next tile; hides under MFMA below
            const int ko = kt + BK;
            v[0] = *(const f4*)(pa0 + ko);
            v[1] = *(const f4*)(pa1 + ko);
            v[2] = *(const f4*)(pb0 + ko);
            v[3] = *(const f4*)(pb1 + ko);
            v[4] = *(const f4*)(pb2 + ko);
        }

        h8 ah[2], al[2], bh[3], bl[3];
#pragma unroll
        for (int mi = 0; mi < 2; ++mi) {
            const int r = m0 + mi * 16 + lr;
            ah[mi] = *(const h8*)(Ah + r * LDST + lq * 8);
            al[mi] = *(const h8*)(Al + r * LDST + lq * 8);
        }
#pragma unroll
        for (int ni = 0; ni < 3; ++ni) {
            const int r = n0 + ni * 16 + lr;
            bh[ni] = *(const h8*)(Bh + r * LDST + lq * 8);
            bl[ni] = *(const h8*)(Bl + r * LDST + lq * 8);
        }
#pragma unroll
        for (int mi = 0; mi < 2; ++mi)
#pragma unroll
            for (int ni = 0; ni < 3; ++ni) {
                acc_h[mi][ni] = __builtin_amdgcn_mfma_f32_16x16x32_f16(ah[mi], bh[ni], acc_h[mi][ni], 0, 0, 0);
                acc_c[mi][ni] = __builtin_amdgcn_mfma_f32_16x16x32_f16(ah[mi], bl[ni], acc_c[mi][ni], 0, 0, 0);
                acc_c[mi][ni] = __builtin_amdgcn_mfma_f32_16x16x32_f16(al[mi], bh[ni], acc_c[mi][ni], 0, 0, 0);
            }
    }

    // C/D layout: col = lane&15, row = (lane>>4)*4 + reg
#pragma unroll
    for (int mi = 0; mi < 2; ++mi)
#pragma unroll
        for (int ni = 0; ni < 3; ++ni)
#pragma unroll
            for (int r = 0; r < 4; ++r) {
                const int gm = bm + m0 + mi * 16 + lq * 4 + r;
                const int gn = bn + n0 + ni * 16 + lr;
                L[(size_t)gm * EXPERTS + gn] = acc_h[mi][ni][r] + acc_c[mi][ni][r] * LO_INV;
            }
}

// One wave per token: softmax over 768, bias-corrected top-12 (desc, ties -> lower idx).
__global__ __launch_bounds__(256)
void router_topk(const float* __restrict__ L, const float* __restrict__ bias,
                 float* __restrict__ outIdx, float* __restrict__ outW) {
    __shared__ float sb[EXPERTS];
    const int t = threadIdx.x;
    for (int i = t; i < EXPERTS; i += 256) sb[i] = bias[i];
    __syncthreads();

    const int lane  = t & 63;
    const int wave  = t >> 6;
    const int token = blockIdx.x * 4 + wave;
    const float* row = L + (size_t)token * EXPERTS;

    float lg[12];
#pragma unroll
    for (int j = 0; j < 12; ++j) lg[j] = row[lane + 64 * j];

    float m = lg[0];
#pragma unroll
    for (int j = 1; j < 12; ++j) m = fmaxf(m, lg[j]);
#pragma unroll
    for (int o = 32; o > 0; o >>= 1) m = fmaxf(m, __shfl_xor(m, o));

    float s = 0.0f;
#pragma unroll
    for (int j = 0; j < 12; ++j) { lg[j] = __expf(lg[j] - m); s += lg[j]; }
#pragma unroll
    for (int o = 32; o > 0; o >>= 1) s += __shfl_xor(s, o);
    const float inv = 1.0f / s;

    float cand[12];
#pragma unroll
    for (int j = 0; j < 12; ++j) {
        lg[j] *= inv;                          // softmax score
        cand[j] = lg[j] + sb[lane + 64 * j];   // biased choice score
    }

#pragma unroll
    for (int r = 0; r < TOPK; ++r) {
        float bv = -__builtin_inff();
        int   bi = EXPERTS;
#pragma unroll
        for (int j = 0; j < 12; ++j) {
            const int e = lane + 64 * j;
            const bool better = (cand[j] > bv) || (cand[j] == bv && e < bi);
            bv = better ? cand[j] : bv;
            bi = better ? e : bi;
        }
#pragma unroll
        for (int o = 32; o > 0; o >>= 1) {
            const float ov = __shfl_xor(bv, o);
            const int   oi = __shfl_xor(bi, o);
            const bool better = (ov > bv) || (ov == bv && oi < bi);
            bv = better ? ov : bv;
            bi = better ? oi : bi;
        }
        if (lane == 0) {
            outIdx[token * TOPK + r] = (float)bi;
            outW  [token * TOPK + r] = (bv - sb[bi]) * RSF;
        }
        if ((bi & 63) == lane) {
            const int slot = bi >> 6;
#pragma unroll
            for (int j = 0; j < 12; ++j)
                if (j == slot) cand[j] = -__builtin_inff();
        }
    }
}

extern "C" void kernel_launch(void* const* d_in, const int* in_sizes, int n_in,
                              void* d_out, int out_size, void* d_ws, size_t ws_size,
                              hipStream_t stream) {
    const float* X = (const float*)d_in[0];   // [8192, 6144] fp32
    const float* W = (const float*)d_in[1];   // [768, 6144]  fp32
    const float* B = (const float*)d_in[2];   // [768]        fp32

    float* logits = (float*)d_ws;             // 8192*768*4 = 25.2 MB scratch
    float* outIdx = (float*)d_out;            // indices as float values
    float* outW   = outIdx + (size_t)TOKENS * TOPK;

    dim3 grid_gemm(EXPERTS / BN, TOKENS / BM);   // (8, 128) = 1024 blocks = 4/CU
    router_gemm<<<grid_gemm, 256, 0, stream>>>(X, W, logits);
    router_topk<<<TOKENS / 4, 256, 0, stream>>>(logits, B, outIdx, outW);
}

// Round 4
// 545.856 us; speedup vs baseline: 1.1885x; 1.0388x over previous
//
#include <hip/hip_runtime.h>

#define TOKENS  8192
#define HIDDEN  6144
#define EXPERTS 768
#define TOPK    12
#define RSF     2.5f
#define ROWH    (HIDDEN * 2)        // halves per row after split-conversion (same bytes as fp32)

typedef float    f4 __attribute__((ext_vector_type(4)));
typedef _Float16 h8 __attribute__((ext_vector_type(8)));
typedef _Float16 h2 __attribute__((ext_vector_type(2)));
typedef __fp16   g2 __attribute__((ext_vector_type(2)));

#define BM 128
#define BN 96
#define BK 64
#define NKT (HIDDEN / BK)           // 96 K-tiles
#define LO_SCALE 4096.0f            // 2^12 keeps lo out of fp16-denormal range
#define LO_INV   2.44140625e-4f     // 2^-12

static __device__ inline h2 pk(float a, float b) {
    g2 r = __builtin_amdgcn_cvt_pkrtz(a, b);
    return __builtin_bit_cast(h2, r);
}

// 8 fp32 -> hi fp16x8 (RTZ) + lo fp16x8 ((x-hi)*2^12)
static __device__ inline void cvt8(const f4 a, const f4 b, h8& hi, h8& lo) {
    h2 ha = pk(a.x, a.y), hb = pk(a.z, a.w), hc = pk(b.x, b.y), hd = pk(b.z, b.w);
    h2 la = pk((a.x - (float)ha[0]) * LO_SCALE, (a.y - (float)ha[1]) * LO_SCALE);
    h2 lb = pk((a.z - (float)hb[0]) * LO_SCALE, (a.w - (float)hb[1]) * LO_SCALE);
    h2 lc = pk((b.x - (float)hc[0]) * LO_SCALE, (b.y - (float)hc[1]) * LO_SCALE);
    h2 ld = pk((b.z - (float)hd[0]) * LO_SCALE, (b.w - (float)hd[1]) * LO_SCALE);
    hi[0]=ha[0]; hi[1]=ha[1]; hi[2]=hb[0]; hi[3]=hb[1];
    hi[4]=hc[0]; hi[5]=hc[1]; hi[6]=hd[0]; hi[7]=hd[1];
    lo[0]=la[0]; lo[1]=la[1]; lo[2]=lb[0]; lo[3]=lb[1];
    lo[4]=lc[0]; lo[5]=lc[1]; lo[6]=ld[0]; lo[7]=ld[1];
}

// In-place fp32 -> [8 hi | 8 lo] fp16 per 8-element group, for X then W.
__global__ __launch_bounds__(256)
void split_convert(float* __restrict__ X, float* __restrict__ W) {
    const size_t GX = (size_t)TOKENS * HIDDEN / 8;
    const size_t GW = (size_t)EXPERTS * HIDDEN / 8;
    size_t gid = (size_t)blockIdx.x * 256 + threadIdx.x;
    if (gid >= GX + GW) return;
    float* base; size_t loc;
    if (gid < GX) { base = X; loc = gid; } else { base = W; loc = gid - GX; }
    const f4* p = (const f4*)(base + loc * 8);
    f4 a = p[0], b = p[1];
    h8 hi, lo;
    cvt8(a, b, hi, lo);
    h8* o = (h8*)(base + loc * 8);
    o[0] = hi; o[1] = lo;
}

typedef __attribute__((address_space(1))) const void av1;
typedef __attribute__((address_space(3))) void av3;
static __device__ inline void stage16(const void* g, void* l) {
    __builtin_amdgcn_global_load_lds((av1*)g, (av3*)l, 16, 0, 0);
}

// logits = Xs · Ws^T via split-fp16 MFMA (hi*hi + hi*lo + lo*hi), m97-style staging.
// LDS: 224 rows (128 A + 96 B) x 8 slots x 16 B, hi region then lo region.
// Swizzle: data group g of row r stored at slot g ^ (r&7)  -> writes sequential,
// ds_read_b128 exactly 2-way per bank (free).
__global__ __launch_bounds__(256, 2)
void router_gemm(const _Float16* __restrict__ Xs, const _Float16* __restrict__ Ws,
                 float* __restrict__ L) {
    __shared__ _Float16 sm[224 * 64 * 2];   // 57344 B; hi halves [0,14336), lo [14336,28672)

    const int t    = threadIdx.x;
    const int bm   = blockIdx.y * BM;
    const int bn   = blockIdx.x * BN;
    const int lane = t & 63;
    const int w    = t >> 6;
    const int lr   = lane & 15;
    const int lq   = lane >> 4;

    // ---- staging assignment: waves 0,1 stage all 28 hi instrs, waves 2,3 all lo
    const int isLo = w >> 1;
    const int jb   = (w & 1) * 14;
    const int lr8  = lane >> 3;        // row within 8-row instr
    const int gs   = lane & 7;         // LDS slot this lane fills

    const _Float16* ps[14];
    uint32_t        ldso[14];
#pragma unroll
    for (int q = 0; q < 14; ++q) {
        const int j = jb + q;                  // 0..27
        const int r = j * 8 + lr8;             // 0..223
        const int g = gs ^ (r & 7);            // source k-group for this slot
        const _Float16* row = (r < BM) ? (Xs + (size_t)(bm + r) * ROWH)
                                       : (Ws + (size_t)(bn + r - BM) * ROWH);
        ps[q]   = row + g * 16 + isLo * 8;     // halves
        ldso[q] = (uint32_t)(isLo * 14336 + j * 512);  // halves (wave-uniform)
    }

    // ---- fragment LDS offsets (halves), constant across K
    uint32_t aoff[4][2], boff[3][2];
#pragma unroll
    for (int mi = 0; mi < 4; ++mi) {
        const int r = (w & 1) * 64 + mi * 16 + lr;
#pragma unroll
        for (int ks = 0; ks < 2; ++ks)
            aoff[mi][ks] = r * 64 + (((ks * 4 + lq) ^ (r & 7)) * 8);
    }
#pragma unroll
    for (int ni = 0; ni < 3; ++ni) {
        const int r = 128 + (w >> 1) * 48 + ni * 16 + lr;
#pragma unroll
        for (int ks = 0; ks < 2; ++ks)
            boff[ni][ks] = r * 64 + (((ks * 4 + lq) ^ (r & 7)) * 8);
    }

    f4 acc_h[4][3], acc_c[4][3];
#pragma unroll
    for (int i = 0; i < 4; ++i)
#pragma unroll
        for (int j = 0; j < 3; ++j) { acc_h[i][j] = f4{0,0,0,0}; acc_c[i][j] = f4{0,0,0,0}; }

    for (int T = 0; T < NKT; ++T) {
        __syncthreads();               // previous tile's LDS reads done
#pragma unroll
        for (int q = 0; q < 14; ++q) {
            stage16((const void*)ps[q], (void*)(sm + ldso[q]));
            ps[q] += 128;              // next K-tile: 8 groups x 16 halves
        }
        __syncthreads();               // drains vmcnt(0): staged data visible

#pragma unroll
        for (int ks = 0; ks < 2; ++ks) {
            h8 ah[4], al[4], bh[3], bl[3];
#pragma unroll
            for (int mi = 0; mi < 4; ++mi) {
                ah[mi] = *(const h8*)(sm + aoff[mi][ks]);
                al[mi] = *(const h8*)(sm + aoff[mi][ks] + 14336);
            }
#pragma unroll
            for (int ni = 0; ni < 3; ++ni) {
                bh[ni] = *(const h8*)(sm + boff[ni][ks]);
                bl[ni] = *(const h8*)(sm + boff[ni][ks] + 14336);
            }
#pragma unroll
            for (int mi = 0; mi < 4; ++mi)
#pragma unroll
                for (int ni = 0; ni < 3; ++ni) {
                    acc_h[mi][ni] = __builtin_amdgcn_mfma_f32_16x16x32_f16(ah[mi], bh[ni], acc_h[mi][ni], 0, 0, 0);
                    acc_c[mi][ni] = __builtin_amdgcn_mfma_f32_16x16x32_f16(ah[mi], bl[ni], acc_c[mi][ni], 0, 0, 0);
                    acc_c[mi][ni] = __builtin_amdgcn_mfma_f32_16x16x32_f16(al[mi], bh[ni], acc_c[mi][ni], 0, 0, 0);
                }
        }
    }

    // C/D layout: col = lane&15, row = (lane>>4)*4 + reg
#pragma unroll
    for (int mi = 0; mi < 4; ++mi)
#pragma unroll
        for (int ni = 0; ni < 3; ++ni)
#pragma unroll
            for (int r = 0; r < 4; ++r) {
                const int gm = bm + (w & 1) * 64 + mi * 16 + lq * 4 + r;
                const int gn = bn + (w >> 1) * 48 + ni * 16 + lr;
                L[(size_t)gm * EXPERTS + gn] = acc_h[mi][ni][r] + acc_c[mi][ni][r] * LO_INV;
            }
}

// One wave per token: softmax over 768, bias-corrected top-12 (desc, ties -> lower idx).
__global__ __launch_bounds__(256)
void router_topk(const float* __restrict__ L, const float* __restrict__ bias,
                 float* __restrict__ outIdx, float* __restrict__ outW) {
    __shared__ float sb[EXPERTS];
    const int t = threadIdx.x;
    for (int i = t; i < EXPERTS; i += 256) sb[i] = bias[i];
    __syncthreads();

    const int lane  = t & 63;
    const int wave  = t >> 6;
    const int token = blockIdx.x * 4 + wave;
    const float* row = L + (size_t)token * EXPERTS;

    float lg[12];
#pragma unroll
    for (int j = 0; j < 12; ++j) lg[j] = row[lane + 64 * j];

    float m = lg[0];
#pragma unroll
    for (int j = 1; j < 12; ++j) m = fmaxf(m, lg[j]);
#pragma unroll
    for (int o = 32; o > 0; o >>= 1) m = fmaxf(m, __shfl_xor(m, o));

    float s = 0.0f;
#pragma unroll
    for (int j = 0; j < 12; ++j) { lg[j] = __expf(lg[j] - m); s += lg[j]; }
#pragma unroll
    for (int o = 32; o > 0; o >>= 1) s += __shfl_xor(s, o);
    const float inv = 1.0f / s;

    float cand[12];
#pragma unroll
    for (int j = 0; j < 12; ++j) {
        lg[j] *= inv;
        cand[j] = lg[j] + sb[lane + 64 * j];
    }

#pragma unroll
    for (int r = 0; r < TOPK; ++r) {
        float bv = -__builtin_inff();
        int   bi = EXPERTS;
#pragma unroll
        for (int j = 0; j < 12; ++j) {
            const int e = lane + 64 * j;
            const bool better = (cand[j] > bv) || (cand[j] == bv && e < bi);
            bv = better ? cand[j] : bv;
            bi = better ? e : bi;
        }
#pragma unroll
        for (int o = 32; o > 0; o >>= 1) {
            const float ov = __shfl_xor(bv, o);
            const int   oi = __shfl_xor(bi, o);
            const bool better = (ov > bv) || (ov == bv && oi < bi);
            bv = better ? ov : bv;
            bi = better ? oi : bi;
        }
        if (lane == 0) {
            outIdx[token * TOPK + r] = (float)bi;
            outW  [token * TOPK + r] = (bv - sb[bi]) * RSF;
        }
        if ((bi & 63) == lane) {
            const int slot = bi >> 6;
#pragma unroll
            for (int j = 0; j < 12; ++j)
                if (j == slot) cand[j] = -__builtin_inff();
        }
    }
}

extern "C" void kernel_launch(void* const* d_in, const int* in_sizes, int n_in,
                              void* d_out, int out_size, void* d_ws, size_t ws_size,
                              hipStream_t stream) {
    float* X = (float*)d_in[0];   // [8192, 6144] fp32 -> split fp16 in place
    float* W = (float*)d_in[1];   // [768, 6144]  fp32 -> split fp16 in place
    const float* B = (const float*)d_in[2];

    float* logits = (float*)d_ws;             // 25.2 MB scratch
    float* outIdx = (float*)d_out;            // indices as float values
    float* outW   = outIdx + (size_t)TOKENS * TOPK;

    const int ngroups = (TOKENS + EXPERTS) * HIDDEN / 8;      // 6881280
    split_convert<<<ngroups / 256, 256, 0, stream>>>(X, W);

    dim3 grid_gemm(EXPERTS / BN, TOKENS / BM);                // (8, 64) = 512 blocks
    router_gemm<<<grid_gemm, 256, 0, stream>>>((const _Float16*)X, (const _Float16*)W, logits);
    router_topk<<<TOKENS / 4, 256, 0, stream>>>(logits, B, outIdx, outW);
}

// Round 5
// 544.065 us; speedup vs baseline: 1.1924x; 1.0033x over previous
//
#include <hip/hip_runtime.h>

#define TOKENS  8192
#define HIDDEN  6144
#define EXPERTS 768
#define TOPK    12
#define RSF     2.5f
#define ROWH    (HIDDEN * 2)        // halves per row after split-conversion

typedef float    f4 __attribute__((ext_vector_type(4)));
typedef _Float16 h8 __attribute__((ext_vector_type(8)));
typedef _Float16 h2 __attribute__((ext_vector_type(2)));
typedef __fp16   g2 __attribute__((ext_vector_type(2)));

#define BM 128
#define BN 96
#define BK 32
#define NKT (HIDDEN / BK)           // 192 K-tiles
#define BUFH 14336                  // halves per LDS buffer (28672 B)
#define LOH  7168                   // halves offset of lo region within buffer
#define LO_SCALE 4096.0f            // 2^12 keeps lo out of fp16-denormal range
#define LO_INV   2.44140625e-4f     // 2^-12

static __device__ inline h2 pk(float a, float b) {
    g2 r = __builtin_amdgcn_cvt_pkrtz(a, b);
    return __builtin_bit_cast(h2, r);
}

// 8 fp32 -> hi fp16x8 (RTZ) + lo fp16x8 ((x-hi)*2^12)
static __device__ inline void cvt8(const f4 a, const f4 b, h8& hi, h8& lo) {
    h2 ha = pk(a.x, a.y), hb = pk(a.z, a.w), hc = pk(b.x, b.y), hd = pk(b.z, b.w);
    h2 la = pk((a.x - (float)ha[0]) * LO_SCALE, (a.y - (float)ha[1]) * LO_SCALE);
    h2 lb = pk((a.z - (float)hb[0]) * LO_SCALE, (a.w - (float)hb[1]) * LO_SCALE);
    h2 lc = pk((b.x - (float)hc[0]) * LO_SCALE, (b.y - (float)hc[1]) * LO_SCALE);
    h2 ld = pk((b.z - (float)hd[0]) * LO_SCALE, (b.w - (float)hd[1]) * LO_SCALE);
    hi[0]=ha[0]; hi[1]=ha[1]; hi[2]=hb[0]; hi[3]=hb[1];
    hi[4]=hc[0]; hi[5]=hc[1]; hi[6]=hd[0]; hi[7]=hd[1];
    lo[0]=la[0]; lo[1]=la[1]; lo[2]=lb[0]; lo[3]=lb[1];
    lo[4]=lc[0]; lo[5]=lc[1]; lo[6]=ld[0]; lo[7]=ld[1];
}

// In-place fp32 -> [8 hi | 8 lo] fp16 per 8-element group, for X then W.
__global__ __launch_bounds__(256)
void split_convert(float* __restrict__ X, float* __restrict__ W) {
    const size_t GX = (size_t)TOKENS * HIDDEN / 8;
    const size_t GW = (size_t)EXPERTS * HIDDEN / 8;
    size_t gid = (size_t)blockIdx.x * 256 + threadIdx.x;
    if (gid >= GX + GW) return;
    float* base; size_t loc;
    if (gid < GX) { base = X; loc = gid; } else { base = W; loc = gid - GX; }
    const f4* p = (const f4*)(base + loc * 8);
    f4 a = p[0], b = p[1];
    h8 hi, lo;
    cvt8(a, b, hi, lo);
    h8* o = (h8*)(base + loc * 8);
    o[0] = hi; o[1] = lo;
}

typedef __attribute__((address_space(1))) const void av1;
typedef __attribute__((address_space(3))) void av3;
static __device__ inline void stage16(const void* g, void* l) {
    __builtin_amdgcn_global_load_lds((av1*)g, (av3*)l, 16, 0, 0);
}

// logits = Xs · Ws^T via split-fp16 MFMA, single-barrier double-buffered K-loop.
// Per 28 KB buffer: 224 rows (128 A + 96 B) x 4 slots x 16 B hi, then lo region.
// Swizzle: group g of row r at slot g ^ (r&3): staging writes sequential,
// ds_read_b128 uniform 8 words/bank.
__global__ __launch_bounds__(256, 2)
void router_gemm(const _Float16* __restrict__ Xs, const _Float16* __restrict__ Ws,
                 float* __restrict__ L) {
    __shared__ _Float16 sm[2 * BUFH];   // 57344 B, two buffers

    const int t    = threadIdx.x;
    const int bm   = blockIdx.y * BM;
    const int bn   = blockIdx.x * BN;
    const int lane = t & 63;
    const int w    = t >> 6;
    const int lr   = lane & 15;
    const int lq   = lane >> 4;        // 0..3 = k-group

    // ---- staging: 28 instrs/tile, 7 per wave
    const _Float16* ps[7];
    uint32_t        ldso[7];           // halves, buffer-relative (wave-uniform)
#pragma unroll
    for (int q = 0; q < 7; ++q) {
        const int j    = w * 7 + q;            // 0..27
        const int isLo = (j >= 14);
        const int jj   = isLo ? j - 14 : j;
        const int r    = jj * 16 + (lane >> 2);
        const int p    = lane & 3;
        const int g    = p ^ (r & 3);          // source k-group for this slot
        const _Float16* row = (r < BM) ? (Xs + (size_t)(bm + r) * ROWH)
                                       : (Ws + (size_t)(bn + r - BM) * ROWH);
        ps[q]   = row + g * 16 + isLo * 8;
        ldso[q] = (uint32_t)(isLo * LOH + jj * 512);
    }

    // ---- fragment LDS offsets (halves, buffer-relative)
    uint32_t aoff[4], boff[3];
#pragma unroll
    for (int mi = 0; mi < 4; ++mi) {
        const int r = (w & 1) * 64 + mi * 16 + lr;
        aoff[mi] = r * 32 + ((lq ^ (r & 3)) * 8);
    }
#pragma unroll
    for (int ni = 0; ni < 3; ++ni) {
        const int r = 128 + (w >> 1) * 48 + ni * 16 + lr;
        boff[ni] = r * 32 + ((lq ^ (r & 3)) * 8);
    }

    f4 acc_h[4][3], acc_c[4][3];
#pragma unroll
    for (int i = 0; i < 4; ++i)
#pragma unroll
        for (int j = 0; j < 3; ++j) { acc_h[i][j] = f4{0,0,0,0}; acc_c[i][j] = f4{0,0,0,0}; }

    // prologue: stage tile 0 into buffer 0
#pragma unroll
    for (int q = 0; q < 7; ++q) {
        stage16((const void*)ps[q], (void*)(sm + ldso[q]));
        ps[q] += 64;
    }

    auto do_tile = [&](const uint32_t boR, const uint32_t boW, const bool doStage) {
        if (doStage) {
#pragma unroll
            for (int q = 0; q < 7; ++q) {
                stage16((const void*)ps[q], (void*)(sm + boW + ldso[q]));
                ps[q] += 64;
            }
        }
        h8 ah[4], al[4], bh[3], bl[3];
#pragma unroll
        for (int mi = 0; mi < 4; ++mi) {
            ah[mi] = *(const h8*)(sm + boR + aoff[mi]);
            al[mi] = *(const h8*)(sm + boR + aoff[mi] + LOH);
        }
#pragma unroll
        for (int ni = 0; ni < 3; ++ni) {
            bh[ni] = *(const h8*)(sm + boR + boff[ni]);
            bl[ni] = *(const h8*)(sm + boR + boff[ni] + LOH);
        }
#pragma unroll
        for (int mi = 0; mi < 4; ++mi)
#pragma unroll
            for (int ni = 0; ni < 3; ++ni) {
                acc_h[mi][ni] = __builtin_amdgcn_mfma_f32_16x16x32_f16(ah[mi], bh[ni], acc_h[mi][ni], 0, 0, 0);
                acc_c[mi][ni] = __builtin_amdgcn_mfma_f32_16x16x32_f16(ah[mi], bl[ni], acc_c[mi][ni], 0, 0, 0);
                acc_c[mi][ni] = __builtin_amdgcn_mfma_f32_16x16x32_f16(al[mi], bh[ni], acc_c[mi][ni], 0, 0, 0);
            }
    };

    for (int T2 = 0; T2 < NKT / 2; ++T2) {
        __syncthreads();                       // tile 2T staged; prev buf1 reads done
        do_tile(0u, (uint32_t)BUFH, true);     // read buf0, stage 2T+1 -> buf1
        __syncthreads();                       // tile 2T+1 staged; buf0 reads done
        do_tile((uint32_t)BUFH, 0u, T2 != NKT / 2 - 1);  // read buf1, stage 2T+2 -> buf0
    }

    // C/D layout: col = lane&15, row = (lane>>4)*4 + reg
#pragma unroll
    for (int mi = 0; mi < 4; ++mi)
#pragma unroll
        for (int ni = 0; ni < 3; ++ni)
#pragma unroll
            for (int r = 0; r < 4; ++r) {
                const int gm = bm + (w & 1) * 64 + mi * 16 + lq * 4 + r;
                const int gn = bn + (w >> 1) * 48 + ni * 16 + lr;
                L[(size_t)gm * EXPERTS + gn] = acc_h[mi][ni][r] + acc_c[mi][ni][r] * LO_INV;
            }
}

// One wave per token: softmax over 768, bias-corrected top-12 (desc, ties -> lower idx).
__global__ __launch_bounds__(256)
void router_topk(const float* __restrict__ L, const float* __restrict__ bias,
                 float* __restrict__ outIdx, float* __restrict__ outW) {
    __shared__ float sb[EXPERTS];
    const int t = threadIdx.x;
    for (int i = t; i < EXPERTS; i += 256) sb[i] = bias[i];
    __syncthreads();

    const int lane  = t & 63;
    const int wave  = t >> 6;
    const int token = blockIdx.x * 4 + wave;
    const float* row = L + (size_t)token * EXPERTS;

    float lg[12];
#pragma unroll
    for (int j = 0; j < 12; ++j) lg[j] = row[lane + 64 * j];

    float m = lg[0];
#pragma unroll
    for (int j = 1; j < 12; ++j) m = fmaxf(m, lg[j]);
#pragma unroll
    for (int o = 32; o > 0; o >>= 1) m = fmaxf(m, __shfl_xor(m, o));

    float s = 0.0f;
#pragma unroll
    for (int j = 0; j < 12; ++j) { lg[j] = __expf(lg[j] - m); s += lg[j]; }
#pragma unroll
    for (int o = 32; o > 0; o >>= 1) s += __shfl_xor(s, o);
    const float inv = 1.0f / s;

    float cand[12];
#pragma unroll
    for (int j = 0; j < 12; ++j) {
        lg[j] *= inv;
        cand[j] = lg[j] + sb[lane + 64 * j];
    }

#pragma unroll
    for (int r = 0; r < TOPK; ++r) {
        float bv = -__builtin_inff();
        int   bi = EXPERTS;
#pragma unroll
        for (int j = 0; j < 12; ++j) {
            const int e = lane + 64 * j;
            const bool better = (cand[j] > bv) || (cand[j] == bv && e < bi);
            bv = better ? cand[j] : bv;
            bi = better ? e : bi;
        }
#pragma unroll
        for (int o = 32; o > 0; o >>= 1) {
            const float ov = __shfl_xor(bv, o);
            const int   oi = __shfl_xor(bi, o);
            const bool better = (ov > bv) || (ov == bv && oi < bi);
            bv = better ? ov : bv;
            bi = better ? oi : bi;
        }
        if (lane == 0) {
            outIdx[token * TOPK + r] = (float)bi;
            outW  [token * TOPK + r] = (bv - sb[bi]) * RSF;
        }
        if ((bi & 63) == lane) {
            const int slot = bi >> 6;
#pragma unroll
            for (int j = 0; j < 12; ++j)
                if (j == slot) cand[j] = -__builtin_inff();
        }
    }
}

extern "C" void kernel_launch(void* const* d_in, const int* in_sizes, int n_in,
                              void* d_out, int out_size, void* d_ws, size_t ws_size,
                              hipStream_t stream) {
    float* X = (float*)d_in[0];   // [8192, 6144] fp32 -> split fp16 in place
    float* W = (float*)d_in[1];   // [768, 6144]  fp32 -> split fp16 in place
    const float* B = (const float*)d_in[2];

    float* logits = (float*)d_ws;             // 25.2 MB scratch
    float* outIdx = (float*)d_out;            // indices as float values
    float* outW   = outIdx + (size_t)TOKENS * TOPK;

    const int ngroups = (TOKENS + EXPERTS) * HIDDEN / 8;      // 6881280
    split_convert<<<ngroups / 256, 256, 0, stream>>>(X, W);

    dim3 grid_gemm(EXPERTS / BN, TOKENS / BM);                // (8, 64) = 512 blocks
    router_gemm<<<grid_gemm, 256, 0, stream>>>((const _Float16*)X, (const _Float16*)W, logits);
    router_topk<<<TOKENS / 4, 256, 0, stream>>>(logits, B, outIdx, outW);
}